// Round 9
// baseline (544.021 us; speedup 1.0000x reference)
//
#include <hip/hip_runtime.h>

#define B_    32
#define P_    197
#define D_    768
#define H_    12
#define DH    64
#define PP_   49
#define NREF  16
#define NP_   784   // NREF*PP_
#define TOPK_ 8
#define EPS_  1e-6f
#define NEGF  -1e30f
#define SCALE 0.125f   // QK_SCALE * d^-0.5

#define IT    8
#define NIT   25    // ceil(197/8)
#define NJ    13    // number of 64-col groups covering 784 (j=12 partial)
#define NROW  (B_ * P_)   // 6304 rows per tensor

__device__ inline float waveReduceMax(float v) {
    #pragma unroll
    for (int off = 32; off; off >>= 1) v = fmaxf(v, __shfl_xor(v, off, 64));
    return v;
}
__device__ inline float waveReduceSum(float v) {
    #pragma unroll
    for (int off = 32; off; off >>= 1) v += __shfl_xor(v, off, 64);
    return v;
}
__device__ inline int waveReduceSumI(int v) {
    #pragma unroll
    for (int off = 32; off; off >>= 1) v += __shfl_xor(v, off, 64);
    return v;
}

// ---------------- K1: fused RMSNorm for q,k,v (one launch instead of three)
__global__ __launch_bounds__(256) void rmsnorm3_kernel(
    const float* __restrict__ q, const float* __restrict__ k,
    const float* __restrict__ v, const float* __restrict__ wq,
    const float* __restrict__ wk, const float* __restrict__ wv,
    float* __restrict__ qn, float* __restrict__ kn, float* __restrict__ vn) {
    int bid = blockIdx.x;
    int which = bid / NROW;          // 0=q 1=k 2=v (wave-uniform SGPR select)
    int row = bid - which * NROW;
    const float* x = (which == 0) ? q : (which == 1) ? k : v;
    const float* w = (which == 0) ? wq : (which == 1) ? wk : wv;
    float* o       = (which == 0) ? qn : (which == 1) ? kn : vn;
    int t = threadIdx.x;
    const float* xr = x + (size_t)row * D_;
    float v0 = xr[t], v1 = xr[t + 256], v2 = xr[t + 512];
    float ss = v0 * v0 + v1 * v1 + v2 * v2;
    __shared__ float red[4];
    ss = waveReduceSum(ss);
    if ((t & 63) == 0) red[t >> 6] = ss;
    __syncthreads();
    float r = rsqrtf((red[0] + red[1] + red[2] + red[3]) * (1.0f / D_) + EPS_);
    float* orow = o + (size_t)row * D_;
    orow[t]       = v0 * r * w[t];
    orow[t + 256] = v1 * r * w[t + 256];
    orow[t + 512] = v2 * r * w[t + 512];
}

// ---------------- K1b: transpose kn -> knT[(b*H+h)*64+dd][j]
__global__ __launch_bounds__(256) void ktrans_kernel(
    const float* __restrict__ kn, float* __restrict__ knT) {
    __shared__ float tile[64][65];
    int bh = blockIdx.x;
    int h = bh % H_;
    int b = bh / H_;
    int t = threadIdx.x, lane = t & 63, wid = t >> 6;
    for (int j0 = 0; j0 < P_; j0 += 64) {
        __syncthreads();
        for (int r = wid; r < 64; r += 4) {
            int j = j0 + r;
            tile[r][lane] = (j < P_) ? kn[((size_t)(b * P_ + j)) * D_ + h * DH + lane] : 0.f;
        }
        __syncthreads();
        for (int r = wid; r < 64; r += 4) {
            int j = j0 + lane;
            if (j < P_) knT[((size_t)bh * DH + r) * P_ + j] = tile[lane][r];
        }
    }
}

// ---------------- K2: rep row-major [h][col][dd] + transposed f4 [h][kk][col]
__global__ __launch_bounds__(256) void rep_gather_kernel(
    const float* __restrict__ vn, const int* __restrict__ idx,
    float* __restrict__ repRM, float* __restrict__ repTG) {
    int u = blockIdx.x * 256 + threadIdx.x;
    if (u >= H_ * NP_ * DH) return;
    int dd  = u & 63;
    int col = (u >> 6) % NP_;
    int h   = u / (NP_ * DH);
    int nref = col / PP_;
    int jp   = col - nref * PP_;
    float val = vn[((size_t)(nref * P_ + idx[jp])) * D_ + h * DH + dd];
    repRM[u] = val;
    repTG[((size_t)(h * 16 + (dd >> 2)) * NP_ + col) * 4 + (dd & 3)] = val;
}

// ---------------- K3: sim GEMM direct-from-L2 + top-8 + sparse v_aligned
// GEMM: exact round-4 structure (proven: VGPR=56, 5 blocks/CU, VALUBusy 85%).
// HARD CONSTRAINT (round 5): VGPR must stay <= 64.
// Select (round 9): round-8's distinct-max extraction was FAST (288->231 µs)
// but WRONG on ties: random_tkn_idxs is sampled with replacement -> rep has
// exactly-duplicated columns -> reference thr = 8th largest WITH MULTIPLICITY,
// ours was 8th DISTINCT -> absmax 0.0039->0.0327 (passed by tolerance luck).
// Fix: keep the single-chain fast path on a copy tv[], then a one-time
// multiplicity audit (n_ge = #{sv >= thr8}); if n_ge > 8 (duplicate in the
// top-8 region, ~10-15% of rows, wave-uniform) rerun the count-based
// reference-exact extraction. Keep-pass uses pristine sv registers.
// Select-phase live regs (~40) < GEMM high-water (56) -> VGPR unchanged.
__global__ __launch_bounds__(256) void sim_topk_kernel(
    const float* __restrict__ vn, const float* __restrict__ repRM,
    const float* __restrict__ repTG, float* __restrict__ vsum) {
    __shared__ float  simS[IT][NP_ + 1];   // 24.6 KB
    __shared__ float4 vrow4[IT][16];       //  2 KB
    __shared__ int    keptIdx[IT][32];     //  1 KB
    __shared__ int    keptCnt[IT];

    int bid = blockIdx.x;
    int it = bid % NIT;
    int h  = (bid / NIT) % H_;
    int m  = bid / (NIT * H_);
    int i0 = it * IT;
    int t = threadIdx.x, lane = t & 63, w = t >> 6;

    // stage the 8 v rows once (all waves broadcast-read them every kk)
    if (t < IT * 16) {
        int r = t >> 4, kk = t & 15;
        int i = i0 + r;
        float4 val = make_float4(0.f, 0.f, 0.f, 0.f);
        if (i < P_) val = *(const float4*)(vn + ((size_t)(m * P_ + i)) * D_ + h * DH + kk * 4);
        vrow4[r][kk] = val;
    }
    __syncthreads();

    // wave-owned column addresses (clamped; invalid groups masked at epilogue)
    int c0 = lane + 64 * (w + 0);
    int c1 = lane + 64 * (w + 4);
    int c2 = lane + 64 * (w + 8);
    int c3 = lane + 64 * (w + 12);
    int a0 = (c0 < NP_) ? c0 : NP_ - 1;
    int a1 = (c1 < NP_) ? c1 : NP_ - 1;
    int a2 = (c2 < NP_) ? c2 : NP_ - 1;
    int a3 = (c3 < NP_) ? c3 : NP_ - 1;

    const float4* rep4 = (const float4*)repTG + (size_t)h * 16 * NP_;

    float acc[IT][4];
    #pragma unroll
    for (int rr = 0; rr < IT; rr++)
        #pragma unroll
        for (int jj = 0; jj < 4; jj++) acc[rr][jj] = 0.f;

    // barrier-free GEMM loop; unroll 2 bounds in-flight loads (8 float4)
    #pragma unroll 2
    for (int kk = 0; kk < 16; kk++) {
        const float4* rk = rep4 + (size_t)kk * NP_;
        float4 r0 = rk[a0];
        float4 r1 = rk[a1];
        float4 r2 = rk[a2];
        float4 r3 = rk[a3];
        #pragma unroll
        for (int rr = 0; rr < IT; rr++) {
            float4 vv = vrow4[rr][kk];       // wave-uniform b128 broadcast
            acc[rr][0] = fmaf(vv.x, r0.x, acc[rr][0]); acc[rr][0] = fmaf(vv.y, r0.y, acc[rr][0]);
            acc[rr][0] = fmaf(vv.z, r0.z, acc[rr][0]); acc[rr][0] = fmaf(vv.w, r0.w, acc[rr][0]);
            acc[rr][1] = fmaf(vv.x, r1.x, acc[rr][1]); acc[rr][1] = fmaf(vv.y, r1.y, acc[rr][1]);
            acc[rr][1] = fmaf(vv.z, r1.z, acc[rr][1]); acc[rr][1] = fmaf(vv.w, r1.w, acc[rr][1]);
            acc[rr][2] = fmaf(vv.x, r2.x, acc[rr][2]); acc[rr][2] = fmaf(vv.y, r2.y, acc[rr][2]);
            acc[rr][2] = fmaf(vv.z, r2.z, acc[rr][2]); acc[rr][2] = fmaf(vv.w, r2.w, acc[rr][2]);
            acc[rr][3] = fmaf(vv.x, r3.x, acc[rr][3]); acc[rr][3] = fmaf(vv.y, r3.y, acc[rr][3]);
            acc[rr][3] = fmaf(vv.w, r3.w, acc[rr][3]); acc[rr][3] = fmaf(vv.z, r3.z, acc[rr][3]);
        }
    }

    // epilogue: mask + write sim to LDS (coalesced, conflict-free)
    #pragma unroll
    for (int jj = 0; jj < 4; jj++) {
        int j = w + 4 * jj;
        int col = lane + 64 * j;
        if (j < NJ && col < NP_) {
            bool mk = (m < NREF) && (col / PP_ == m);
            #pragma unroll
            for (int rr = 0; rr < IT; rr++)
                simS[rr][col] = mk ? NEGF : acc[rr][jj];
        }
    }
    __syncthreads();

    // top-8 + sparse v_aligned (wave w owns rows w, w+4)
    const float* reph = repRM + (size_t)h * NP_ * DH;
    for (int rr = w; rr < IT; rr += 4) {
        int i = i0 + rr;
        if (i >= P_) continue;
        if (lane == 0) keptCnt[rr] = 0;
        float sv[NJ];
        #pragma unroll
        for (int j = 0; j < NJ; j++) {
            int c = lane + 64 * j;
            sv[j] = (c < NP_) ? simS[rr][c] : NEGF;
        }

        // fast path: destructive distinct-max extraction on a copy
        float tv[NJ];
        #pragma unroll
        for (int j = 0; j < NJ; j++) tv[j] = sv[j];
        float thr = NEGF, vmax = NEGF;
        #pragma unroll
        for (int iter = 0; iter < TOPK_; iter++) {
            float lm = tv[0];
            #pragma unroll
            for (int j = 1; j < NJ; j++) lm = fmaxf(lm, tv[j]);
            float gm = waveReduceMax(lm);
            if (iter == 0) vmax = gm;
            thr = gm;
            if (iter != TOPK_ - 1) {        // compile-time (full unroll)
                #pragma unroll
                for (int j = 0; j < NJ; j++)
                    tv[j] = (tv[j] == gm) ? NEGF : tv[j];
            }
        }
        // multiplicity audit: reference thr = 8th largest WITH multiplicity
        int lc = 0;
        #pragma unroll
        for (int j = 0; j < NJ; j++) lc += (sv[j] >= thr) ? 1 : 0;
        int nge = waveReduceSumI(lc);
        if (nge > TOPK_) {
            // slow path (duplicated rep column in top-8 region): count-based
            // extraction with early exit — exact reference semantics.
            #pragma unroll
            for (int j = 0; j < NJ; j++) tv[j] = sv[j];
            int remaining = TOPK_;
            for (int iter = 0; iter < TOPK_; iter++) {
                float lm = NEGF;
                #pragma unroll
                for (int j = 0; j < NJ; j++) lm = fmaxf(lm, tv[j]);
                float gm = waveReduceMax(lm);
                int lc2 = 0;
                #pragma unroll
                for (int j = 0; j < NJ; j++)
                    if (tv[j] == gm) { lc2++; tv[j] = NEGF; }
                int gc = waveReduceSumI(lc2);
                thr = gm;
                if (gc >= remaining) break;
                remaining -= gc;
            }
        }

        // keep-pass on pristine register copy
        float lsum = 0.f;
        #pragma unroll
        for (int j = 0; j < NJ; j++) {
            if (sv[j] >= thr) {
                lsum += __expf(sv[j] - vmax);
                int slot = atomicAdd(&keptCnt[rr], 1);
                if (slot < 32) keptIdx[rr][slot] = lane + 64 * j;
            }
        }
        float Z = waveReduceSum(lsum);
        float invZ = 1.0f / Z;
        int nk = keptCnt[rr];   // same-wave LDS ops complete in order
        if (nk > 32) nk = 32;
        float acc2 = 0.f;
        for (int z = 0; z < nk; z++) {
            int c = keptIdx[rr][z];
            float s = simS[rr][c];             // uniform addr -> LDS broadcast
            acc2 += __expf(s - vmax) * invZ * reph[(size_t)c * DH + lane];
        }
        vsum[((size_t)((m * H_ + h) * P_) + i) * DH + lane] =
            vn[((size_t)(m * P_ + i)) * D_ + h * DH + lane] + acc2;
    }
}

// ---------------- K4: attention, 8 query rows per block (shared k/vsum loads)
// EXACT round-6 version (proven others ~240 µs). Round-7's XCD swizzle +
// unrolls regressed ~17 µs: the working set is L3-resident, so T1-style
// swizzle is out of its regime (null-to-negative when L3-fit).
__global__ __launch_bounds__(256) void attn_kernel(
    const float* __restrict__ qn, const float* __restrict__ knT,
    const float* __restrict__ vsum, float* __restrict__ out) {
    __shared__ float4 qt4[IT][16];       //  2 KB
    __shared__ float  sc[IT][256];       //  8 KB  scores, [row][j]
    __shared__ float  prowT[256][8];     //  8 KB  softmax probs, [j][row]
    __shared__ float  redvA[IT][256];    //  8 KB  PV partials

    int bid = blockIdx.x;
    int it = bid % NIT;
    int h  = (bid / NIT) % H_;
    int b  = bid / (NIT * H_);
    int i0 = it * IT;
    int t = threadIdx.x, lane = t & 63, w = t >> 6;

    // stage 8 q rows as float4
    if (t < IT * 16) {
        int r = t >> 4, z = t & 15;
        int i = i0 + r;
        float4 val = make_float4(0.f, 0.f, 0.f, 0.f);
        if (i < P_) val = *(const float4*)(qn + ((size_t)(b * P_ + i)) * D_ + h * DH + z * 4);
        qt4[r][z] = val;
    }
    __syncthreads();

    // QK: thread t = column j; one k-load feeds 8 rows
    {
        const float* kTb = knT + (size_t)(b * H_ + h) * DH * P_;
        int j = t;
        int jc = (j < P_) ? j : 0;               // clamp (masked later)
        float acc[IT];
        #pragma unroll
        for (int r = 0; r < IT; r++) acc[r] = 0.f;
        for (int z = 0; z < 16; z++) {
            const float* kp = kTb + (size_t)(4 * z) * P_ + jc;
            float k0 = kp[0 * P_], k1 = kp[1 * P_], k2 = kp[2 * P_], k3 = kp[3 * P_];
            #pragma unroll
            for (int r = 0; r < IT; r++) {
                float4 qv = qt4[r][z];           // wave-uniform b128 broadcast
                acc[r] = fmaf(qv.x, k0, fmaf(qv.y, k1, fmaf(qv.z, k2, fmaf(qv.w, k3, acc[r]))));
            }
        }
        #pragma unroll
        for (int r = 0; r < IT; r++) sc[r][j] = acc[r] * SCALE;
    }
    __syncthreads();

    // softmax: wave w handles rows w, w+4 (wave-local, proven pattern)
    for (int rr = w; rr < IT; rr += 4) {
        float s0[4];
        #pragma unroll
        for (int g = 0; g < 4; g++) {
            int j = lane + 64 * g;
            s0[g] = (j < P_) ? sc[rr][j] : NEGF;
        }
        float mx = fmaxf(fmaxf(s0[0], s0[1]), fmaxf(s0[2], s0[3]));
        mx = waveReduceMax(mx);
        float e[4], ls = 0.f;
        #pragma unroll
        for (int g = 0; g < 4; g++) {
            int j = lane + 64 * g;
            e[g] = (j < P_) ? __expf(s0[g] - mx) : 0.f;
            ls += e[g];
        }
        float Z = waveReduceSum(ls);
        float invZ = 1.0f / Z;
        #pragma unroll
        for (int g = 0; g < 4; g++) prowT[lane + 64 * g][rr] = e[g] * invZ;
    }
    __syncthreads();

    // PV: one vsum load feeds 8 rows via prowT broadcasts
    {
        int dd = t & 63, q4 = t >> 6;
        const float* vb = vsum + (size_t)((b * H_ + h) * P_) * DH;
        float acc[IT];
        #pragma unroll
        for (int r = 0; r < IT; r++) acc[r] = 0.f;
        for (int jj = q4; jj < P_; jj += 4) {
            float vv = vb[(size_t)jj * DH + dd];
            float4 p0 = *(const float4*)&prowT[jj][0];   // wave-uniform broadcasts
            float4 p1 = *(const float4*)&prowT[jj][4];
            acc[0] = fmaf(p0.x, vv, acc[0]);
            acc[1] = fmaf(p0.y, vv, acc[1]);
            acc[2] = fmaf(p0.z, vv, acc[2]);
            acc[3] = fmaf(p0.w, vv, acc[3]);
            acc[4] = fmaf(p1.x, vv, acc[4]);
            acc[5] = fmaf(p1.y, vv, acc[5]);
            acc[6] = fmaf(p1.z, vv, acc[6]);
            acc[7] = fmaf(p1.w, vv, acc[7]);
        }
        #pragma unroll
        for (int r = 0; r < IT; r++) redvA[r][q4 * 64 + dd] = acc[r];
    }
    __syncthreads();
    if (t < DH) {
        #pragma unroll
        for (int r = 0; r < IT; r++) {
            int i = i0 + r;
            if (i < P_) {
                float o = redvA[r][t] + redvA[r][64 + t] + redvA[r][128 + t] + redvA[r][192 + t];
                out[((size_t)(b * P_ + i)) * D_ + h * DH + t] = o;
            }
        }
    }
}

extern "C" void kernel_launch(void* const* d_in, const int* in_sizes, int n_in,
                              void* d_out, int out_size, void* d_ws, size_t ws_size,
                              hipStream_t stream) {
    const float* q  = (const float*)d_in[0];
    const float* k  = (const float*)d_in[1];
    const float* v  = (const float*)d_in[2];
    const float* wq = (const float*)d_in[3];
    const float* wk = (const float*)d_in[4];
    const float* wv = (const float*)d_in[5];
    const int* idx = (const int*)d_in[6];
    float* out = (float*)d_out;

    const size_t NTOK = (size_t)B_ * P_ * D_;        // 4,841,472
    const size_t REPSZ = (size_t)H_ * NP_ * DH;      // 602,112

    float* p = (float*)d_ws;
    float* qn    = p;  p += NTOK;
    float* kn    = p;  p += NTOK;
    float* knT   = p;  p += NTOK;
    float* repRM = p;  p += REPSZ;
    float* repTG = p;  p += REPSZ;
    float* vsum  = p;  p += NTOK;     // total ~82.3 MB (proven footprint)
    float* vn    = out;               // d_out as scratch: dead before attn writes out

    rmsnorm3_kernel<<<3 * NROW, 256, 0, stream>>>(q, k, v, wq, wk, wv, qn, kn, vn);
    ktrans_kernel<<<B_ * H_, 256, 0, stream>>>(kn, knT);
    rep_gather_kernel<<<(H_ * NP_ * DH + 255) / 256, 256, 0, stream>>>(vn, idx, repRM, repTG);
    sim_topk_kernel<<<B_ * H_ * NIT, 256, 0, stream>>>(vn, repRM, repTG, vsum);
    attn_kernel<<<B_ * H_ * NIT, 256, 0, stream>>>(qn, knT, vsum, out);
}

// Round 10
// 440.725 us; speedup vs baseline: 1.2344x; 1.2344x over previous
//
#include <hip/hip_runtime.h>

#define B_    32
#define P_    197
#define D_    768
#define H_    12
#define DH    64
#define PP_   49
#define NREF  16
#define NP_   784   // NREF*PP_
#define TOPK_ 8
#define EPS_  1e-6f
#define NEGF  -1e30f
#define SCALE 0.125f   // QK_SCALE * d^-0.5

#define IT    8
#define NIT   25    // ceil(197/8)
#define NJ    13    // number of 64-col groups covering 784 (j=12 partial)
#define NROW  (B_ * P_)   // 6304 rows per tensor

__device__ inline float waveReduceMax(float v) {
    #pragma unroll
    for (int off = 32; off; off >>= 1) v = fmaxf(v, __shfl_xor(v, off, 64));
    return v;
}
__device__ inline float waveReduceSum(float v) {
    #pragma unroll
    for (int off = 32; off; off >>= 1) v += __shfl_xor(v, off, 64);
    return v;
}

// ---------------- K1: fused RMSNorm for q,k,v (one launch instead of three)
__global__ __launch_bounds__(256) void rmsnorm3_kernel(
    const float* __restrict__ q, const float* __restrict__ k,
    const float* __restrict__ v, const float* __restrict__ wq,
    const float* __restrict__ wk, const float* __restrict__ wv,
    float* __restrict__ qn, float* __restrict__ kn, float* __restrict__ vn) {
    int bid = blockIdx.x;
    int which = bid / NROW;          // 0=q 1=k 2=v (wave-uniform SGPR select)
    int row = bid - which * NROW;
    const float* x = (which == 0) ? q : (which == 1) ? k : v;
    const float* w = (which == 0) ? wq : (which == 1) ? wk : wv;
    float* o       = (which == 0) ? qn : (which == 1) ? kn : vn;
    int t = threadIdx.x;
    const float* xr = x + (size_t)row * D_;
    float v0 = xr[t], v1 = xr[t + 256], v2 = xr[t + 512];
    float ss = v0 * v0 + v1 * v1 + v2 * v2;
    __shared__ float red[4];
    ss = waveReduceSum(ss);
    if ((t & 63) == 0) red[t >> 6] = ss;
    __syncthreads();
    float r = rsqrtf((red[0] + red[1] + red[2] + red[3]) * (1.0f / D_) + EPS_);
    float* orow = o + (size_t)row * D_;
    orow[t]       = v0 * r * w[t];
    orow[t + 256] = v1 * r * w[t + 256];
    orow[t + 512] = v2 * r * w[t + 512];
}

// ---------------- K1b: transpose kn -> knT[(b*H+h)*64+dd][j]
__global__ __launch_bounds__(256) void ktrans_kernel(
    const float* __restrict__ kn, float* __restrict__ knT) {
    __shared__ float tile[64][65];
    int bh = blockIdx.x;
    int h = bh % H_;
    int b = bh / H_;
    int t = threadIdx.x, lane = t & 63, wid = t >> 6;
    for (int j0 = 0; j0 < P_; j0 += 64) {
        __syncthreads();
        for (int r = wid; r < 64; r += 4) {
            int j = j0 + r;
            tile[r][lane] = (j < P_) ? kn[((size_t)(b * P_ + j)) * D_ + h * DH + lane] : 0.f;
        }
        __syncthreads();
        for (int r = wid; r < 64; r += 4) {
            int j = j0 + lane;
            if (j < P_) knT[((size_t)bh * DH + r) * P_ + j] = tile[lane][r];
        }
    }
}

// ---------------- K2: rep row-major [h][col][dd] + transposed f4 [h][kk][col]
__global__ __launch_bounds__(256) void rep_gather_kernel(
    const float* __restrict__ vn, const int* __restrict__ idx,
    float* __restrict__ repRM, float* __restrict__ repTG) {
    int u = blockIdx.x * 256 + threadIdx.x;
    if (u >= H_ * NP_ * DH) return;
    int dd  = u & 63;
    int col = (u >> 6) % NP_;
    int h   = u / (NP_ * DH);
    int nref = col / PP_;
    int jp   = col - nref * PP_;
    float val = vn[((size_t)(nref * P_ + idx[jp])) * D_ + h * DH + dd];
    repRM[u] = val;
    repTG[((size_t)(h * 16 + (dd >> 2)) * NP_ + col) * 4 + (dd & 3)] = val;
}

// ---------------- K3: sim GEMM direct-from-L2 + top-8 + sparse v_aligned
// GEMM: exact round-4 structure (proven: VGPR=56, 5 blocks/CU).
// HARD CONSTRAINT (round 5): VGPR must stay <= 64.
// Select (round 10): destructive extraction + BALLOT multiplicity.
// Round-9 lesson: duplicates are the COMMON case (~96 dup column pairs from
// idx sampled with replacement -> ~90% of rows have a dup in the top-8
// region), so fast-path+slow-path ran BOTH paths almost always (320 µs).
// Ballot trick: an idx-dup pair lands at cols n*49+jp1 / n*49+jp2 with
// |jp1-jp2| < 49, never congruent mod 64 -> the two copies are ALWAYS in
// different lanes -> multiplicity of current max = popcount(ballot(lane has
// match)). Exact reference tie semantics, ONE shfl chain per iter, SALU
// bookkeeping. ~67 VALU/iter vs round-6's ~81 with two chains.
__global__ __launch_bounds__(256) void sim_topk_kernel(
    const float* __restrict__ vn, const float* __restrict__ repRM,
    const float* __restrict__ repTG, float* __restrict__ vsum) {
    __shared__ float  simS[IT][NP_ + 1];   // 24.6 KB
    __shared__ float4 vrow4[IT][16];       //  2 KB
    __shared__ int    keptIdx[IT][32];     //  1 KB
    __shared__ int    keptCnt[IT];

    int bid = blockIdx.x;
    int it = bid % NIT;
    int h  = (bid / NIT) % H_;
    int m  = bid / (NIT * H_);
    int i0 = it * IT;
    int t = threadIdx.x, lane = t & 63, w = t >> 6;

    // stage the 8 v rows once (all waves broadcast-read them every kk)
    if (t < IT * 16) {
        int r = t >> 4, kk = t & 15;
        int i = i0 + r;
        float4 val = make_float4(0.f, 0.f, 0.f, 0.f);
        if (i < P_) val = *(const float4*)(vn + ((size_t)(m * P_ + i)) * D_ + h * DH + kk * 4);
        vrow4[r][kk] = val;
    }
    __syncthreads();

    // wave-owned column addresses (clamped; invalid groups masked at epilogue)
    int c0 = lane + 64 * (w + 0);
    int c1 = lane + 64 * (w + 4);
    int c2 = lane + 64 * (w + 8);
    int c3 = lane + 64 * (w + 12);
    int a0 = (c0 < NP_) ? c0 : NP_ - 1;
    int a1 = (c1 < NP_) ? c1 : NP_ - 1;
    int a2 = (c2 < NP_) ? c2 : NP_ - 1;
    int a3 = (c3 < NP_) ? c3 : NP_ - 1;

    const float4* rep4 = (const float4*)repTG + (size_t)h * 16 * NP_;

    float acc[IT][4];
    #pragma unroll
    for (int rr = 0; rr < IT; rr++)
        #pragma unroll
        for (int jj = 0; jj < 4; jj++) acc[rr][jj] = 0.f;

    // barrier-free GEMM loop; unroll 2 bounds in-flight loads (8 float4)
    #pragma unroll 2
    for (int kk = 0; kk < 16; kk++) {
        const float4* rk = rep4 + (size_t)kk * NP_;
        float4 r0 = rk[a0];
        float4 r1 = rk[a1];
        float4 r2 = rk[a2];
        float4 r3 = rk[a3];
        #pragma unroll
        for (int rr = 0; rr < IT; rr++) {
            float4 vv = vrow4[rr][kk];       // wave-uniform b128 broadcast
            acc[rr][0] = fmaf(vv.x, r0.x, acc[rr][0]); acc[rr][0] = fmaf(vv.y, r0.y, acc[rr][0]);
            acc[rr][0] = fmaf(vv.z, r0.z, acc[rr][0]); acc[rr][0] = fmaf(vv.w, r0.w, acc[rr][0]);
            acc[rr][1] = fmaf(vv.x, r1.x, acc[rr][1]); acc[rr][1] = fmaf(vv.y, r1.y, acc[rr][1]);
            acc[rr][1] = fmaf(vv.z, r1.z, acc[rr][1]); acc[rr][1] = fmaf(vv.w, r1.w, acc[rr][1]);
            acc[rr][2] = fmaf(vv.x, r2.x, acc[rr][2]); acc[rr][2] = fmaf(vv.y, r2.y, acc[rr][2]);
            acc[rr][2] = fmaf(vv.z, r2.z, acc[rr][2]); acc[rr][2] = fmaf(vv.w, r2.w, acc[rr][2]);
            acc[rr][3] = fmaf(vv.x, r3.x, acc[rr][3]); acc[rr][3] = fmaf(vv.y, r3.y, acc[rr][3]);
            acc[rr][3] = fmaf(vv.z, r3.z, acc[rr][3]); acc[rr][3] = fmaf(vv.w, r3.w, acc[rr][3]);
        }
    }

    // epilogue: mask + write sim to LDS (coalesced, conflict-free)
    #pragma unroll
    for (int jj = 0; jj < 4; jj++) {
        int j = w + 4 * jj;
        int col = lane + 64 * j;
        if (j < NJ && col < NP_) {
            bool mk = (m < NREF) && (col / PP_ == m);
            #pragma unroll
            for (int rr = 0; rr < IT; rr++)
                simS[rr][col] = mk ? NEGF : acc[rr][jj];
        }
    }
    __syncthreads();

    // top-8 + sparse v_aligned (wave w owns rows w, w+4)
    const float* reph = repRM + (size_t)h * NP_ * DH;
    for (int rr = w; rr < IT; rr += 4) {
        int i = i0 + rr;
        if (i >= P_) continue;
        if (lane == 0) keptCnt[rr] = 0;
        float sv[NJ];
        #pragma unroll
        for (int j = 0; j < NJ; j++) {
            int c = lane + 64 * j;
            sv[j] = (c < NP_) ? simS[rr][c] : NEGF;
        }

        // destructive extraction, ballot multiplicity (exact tie semantics)
        float tv[NJ];
        #pragma unroll
        for (int j = 0; j < NJ; j++) tv[j] = sv[j];
        float thr = NEGF, vmax = NEGF;
        int remaining = TOPK_;
        for (int iter = 0; iter < TOPK_; iter++) {
            float lm = tv[0];
            #pragma unroll
            for (int j = 1; j < NJ; j++) lm = fmaxf(lm, tv[j]);
            float gm = waveReduceMax(lm);
            if (iter == 0) vmax = gm;
            thr = gm;
            bool any = false;
            #pragma unroll
            for (int j = 0; j < NJ; j++) {
                bool eq = (tv[j] == gm);
                any = any || eq;
                tv[j] = eq ? NEGF : tv[j];
            }
            // dup copies are always in distinct lanes (cols of an idx-dup
            // pair differ by <49, never ==0 mod 64) -> popcount == count
            unsigned long long bal = __ballot(any);
            int gc = __popcll(bal);
            if (gc >= remaining) break;
            remaining -= gc;
        }

        // keep-pass on pristine register copy
        float lsum = 0.f;
        #pragma unroll
        for (int j = 0; j < NJ; j++) {
            if (sv[j] >= thr) {
                lsum += __expf(sv[j] - vmax);
                int slot = atomicAdd(&keptCnt[rr], 1);
                if (slot < 32) keptIdx[rr][slot] = lane + 64 * j;
            }
        }
        float Z = waveReduceSum(lsum);
        float invZ = 1.0f / Z;
        int nk = keptCnt[rr];   // same-wave LDS ops complete in order
        if (nk > 32) nk = 32;
        float acc2 = 0.f;
        for (int z = 0; z < nk; z++) {
            int c = keptIdx[rr][z];
            float s = simS[rr][c];             // uniform addr -> LDS broadcast
            acc2 += __expf(s - vmax) * invZ * reph[(size_t)c * DH + lane];
        }
        vsum[((size_t)((m * H_ + h) * P_) + i) * DH + lane] =
            vn[((size_t)(m * P_ + i)) * D_ + h * DH + lane] + acc2;
    }
}

// ---------------- K4: attention, 8 query rows per block (shared k/vsum loads)
// Round-6 structure. Single round-10 change: #pragma unroll 4 on the PV
// jj-loop — 49 serial dependent-load iterations previously ran with 1 vsum
// load in flight; 4-deep load pipelining. (Round-7's regression was the XCD
// swizzle — wrong regime, L3-resident working set — not unrolling per se;
// this isolates the unroll variable.)
__global__ __launch_bounds__(256) void attn_kernel(
    const float* __restrict__ qn, const float* __restrict__ knT,
    const float* __restrict__ vsum, float* __restrict__ out) {
    __shared__ float4 qt4[IT][16];       //  2 KB
    __shared__ float  sc[IT][256];       //  8 KB  scores, [row][j]
    __shared__ float  prowT[256][8];     //  8 KB  softmax probs, [j][row]
    __shared__ float  redvA[IT][256];    //  8 KB  PV partials

    int bid = blockIdx.x;
    int it = bid % NIT;
    int h  = (bid / NIT) % H_;
    int b  = bid / (NIT * H_);
    int i0 = it * IT;
    int t = threadIdx.x, lane = t & 63, w = t >> 6;

    // stage 8 q rows as float4
    if (t < IT * 16) {
        int r = t >> 4, z = t & 15;
        int i = i0 + r;
        float4 val = make_float4(0.f, 0.f, 0.f, 0.f);
        if (i < P_) val = *(const float4*)(qn + ((size_t)(b * P_ + i)) * D_ + h * DH + z * 4);
        qt4[r][z] = val;
    }
    __syncthreads();

    // QK: thread t = column j; one k-load feeds 8 rows
    {
        const float* kTb = knT + (size_t)(b * H_ + h) * DH * P_;
        int j = t;
        int jc = (j < P_) ? j : 0;               // clamp (masked later)
        float acc[IT];
        #pragma unroll
        for (int r = 0; r < IT; r++) acc[r] = 0.f;
        for (int z = 0; z < 16; z++) {
            const float* kp = kTb + (size_t)(4 * z) * P_ + jc;
            float k0 = kp[0 * P_], k1 = kp[1 * P_], k2 = kp[2 * P_], k3 = kp[3 * P_];
            #pragma unroll
            for (int r = 0; r < IT; r++) {
                float4 qv = qt4[r][z];           // wave-uniform b128 broadcast
                acc[r] = fmaf(qv.x, k0, fmaf(qv.y, k1, fmaf(qv.z, k2, fmaf(qv.w, k3, acc[r]))));
            }
        }
        #pragma unroll
        for (int r = 0; r < IT; r++) sc[r][j] = acc[r] * SCALE;
    }
    __syncthreads();

    // softmax: wave w handles rows w, w+4 (wave-local, proven pattern)
    for (int rr = w; rr < IT; rr += 4) {
        float s0[4];
        #pragma unroll
        for (int g = 0; g < 4; g++) {
            int j = lane + 64 * g;
            s0[g] = (j < P_) ? sc[rr][j] : NEGF;
        }
        float mx = fmaxf(fmaxf(s0[0], s0[1]), fmaxf(s0[2], s0[3]));
        mx = waveReduceMax(mx);
        float e[4], ls = 0.f;
        #pragma unroll
        for (int g = 0; g < 4; g++) {
            int j = lane + 64 * g;
            e[g] = (j < P_) ? __expf(s0[g] - mx) : 0.f;
            ls += e[g];
        }
        float Z = waveReduceSum(ls);
        float invZ = 1.0f / Z;
        #pragma unroll
        for (int g = 0; g < 4; g++) prowT[lane + 64 * g][rr] = e[g] * invZ;
    }
    __syncthreads();

    // PV: one vsum load feeds 8 rows via prowT broadcasts
    {
        int dd = t & 63, q4 = t >> 6;
        const float* vb = vsum + (size_t)((b * H_ + h) * P_) * DH;
        float acc[IT];
        #pragma unroll
        for (int r = 0; r < IT; r++) acc[r] = 0.f;
        #pragma unroll 4
        for (int jj = q4; jj < P_; jj += 4) {
            float vv = vb[(size_t)jj * DH + dd];
            float4 p0 = *(const float4*)&prowT[jj][0];   // wave-uniform broadcasts
            float4 p1 = *(const float4*)&prowT[jj][4];
            acc[0] = fmaf(p0.x, vv, acc[0]);
            acc[1] = fmaf(p0.y, vv, acc[1]);
            acc[2] = fmaf(p0.z, vv, acc[2]);
            acc[3] = fmaf(p0.w, vv, acc[3]);
            acc[4] = fmaf(p1.x, vv, acc[4]);
            acc[5] = fmaf(p1.y, vv, acc[5]);
            acc[6] = fmaf(p1.z, vv, acc[6]);
            acc[7] = fmaf(p1.w, vv, acc[7]);
        }
        #pragma unroll
        for (int r = 0; r < IT; r++) redvA[r][q4 * 64 + dd] = acc[r];
    }
    __syncthreads();
    if (t < DH) {
        #pragma unroll
        for (int r = 0; r < IT; r++) {
            int i = i0 + r;
            if (i < P_) {
                float o = redvA[r][t] + redvA[r][64 + t] + redvA[r][128 + t] + redvA[r][192 + t];
                out[((size_t)(b * P_ + i)) * D_ + h * DH + t] = o;
            }
        }
    }
}

extern "C" void kernel_launch(void* const* d_in, const int* in_sizes, int n_in,
                              void* d_out, int out_size, void* d_ws, size_t ws_size,
                              hipStream_t stream) {
    const float* q  = (const float*)d_in[0];
    const float* k  = (const float*)d_in[1];
    const float* v  = (const float*)d_in[2];
    const float* wq = (const float*)d_in[3];
    const float* wk = (const float*)d_in[4];
    const float* wv = (const float*)d_in[5];
    const int* idx = (const int*)d_in[6];
    float* out = (float*)d_out;

    const size_t NTOK = (size_t)B_ * P_ * D_;        // 4,841,472
    const size_t REPSZ = (size_t)H_ * NP_ * DH;      // 602,112

    float* p = (float*)d_ws;
    float* qn    = p;  p += NTOK;
    float* kn    = p;  p += NTOK;
    float* knT   = p;  p += NTOK;
    float* repRM = p;  p += REPSZ;
    float* repTG = p;  p += REPSZ;
    float* vsum  = p;  p += NTOK;     // total ~82.3 MB (proven footprint)
    float* vn    = out;               // d_out as scratch: dead before attn writes out

    rmsnorm3_kernel<<<3 * NROW, 256, 0, stream>>>(q, k, v, wq, wk, wv, qn, kn, vn);
    ktrans_kernel<<<B_ * H_, 256, 0, stream>>>(kn, knT);
    rep_gather_kernel<<<(H_ * NP_ * DH + 255) / 256, 256, 0, stream>>>(vn, idx, repRM, repTG);
    sim_topk_kernel<<<B_ * H_ * NIT, 256, 0, stream>>>(vn, repRM, repTG, vsum);
    attn_kernel<<<B_ * H_ * NIT, 256, 0, stream>>>(qn, knT, vsum, out);
}